// Round 15
// baseline (108.195 us; speedup 1.0000x reference)
//
#include <hip/hip_runtime.h>
#include <math.h>

#define LOG2E  1.4426950408889634f
#define LN_EPS 1e-5f

typedef __attribute__((ext_vector_type(8))) short bf16x8;
typedef __attribute__((ext_vector_type(4))) float f32x4;
typedef __attribute__((ext_vector_type(4))) unsigned u32x4;

__device__ __forceinline__ short f2bf(float x) {
    unsigned u = __builtin_bit_cast(unsigned, x);
    u = (u + 0x7FFF + ((u >> 16) & 1)) >> 16;
    return (short)u;
}
__device__ __forceinline__ float bf2f(unsigned short b) {
    return __builtin_bit_cast(float, (unsigned)b << 16);
}

// ---------------------------------------------------------------------------
// ws layout (bytes):
//  q_buf  bf16 [65536][128]      : 16,777,216
//  k_buf  bf16 [65536][128]      : 16,777,216
//  v_t    bf16 [256][128][256]   : 16,777,216   (V transposed per row i)
//  og_buf bf16 [65536][128]      : 16,777,216
//  g_buf  bf16 [65536][128]      : 16,777,216
//  nb2    f32  [4][65536]        :  1,048,576   ([h][q*256+k], ×log2e)
//  nb4    f32  [4][65536]        :  1,048,576   ([h][(q>>2)*1024+k*4+(q&3)])
//  wT     bf16 5*16384+2048      :    167,936   ([mat][col][k]; +w2d tile)
// ---------------------------------------------------------------------------

__global__ __launch_bounds__(256) void prep_kernel(
    const float* __restrict__ wq, const float* __restrict__ wk,
    const float* __restrict__ wv, const float* __restrict__ wg,
    const float* __restrict__ wo, const float* __restrict__ w2d,
    short* __restrict__ wT)
{
    int gid = blockIdx.x * 256 + threadIdx.x;
    if (gid < 5 * 16384) {
        int m = gid >> 14, r = gid & 16383, col = r >> 7, k = r & 127;
        const float* W = (m == 0) ? wq : (m == 1) ? wk : (m == 2) ? wv
                       : (m == 3) ? wg : wo;
        float s = (m == 0) ? (0.17677669529663687f * LOG2E) : 1.0f;
        wT[gid] = f2bf(W[k * 128 + col] * s);
    } else if (gid < 5 * 16384 + 16 * 128) {
        int r = gid - 5 * 16384, col = r >> 7, k = r & 127;
        float v = (col < 4) ? w2d[k * 4 + col] * LOG2E : 0.0f;
        wT[gid] = f2bf(v);
    }
}

// ---------------------------------------------------------------------------
// Kernel 1: LN + projections. 512 blocks (128 positions), 256 thr (4 waves).
// R9-green verbatim (incl. the coalesced f32x4 nb2[h][q*256+k] store).
// ---------------------------------------------------------------------------
__global__ __launch_bounds__(256) void proj_kernel(
    const float* __restrict__ act, const float* __restrict__ ln_w,
    const float* __restrict__ ln_b, const float* __restrict__ bg,
    const short* __restrict__ wT,
    short* __restrict__ q_buf, short* __restrict__ k_buf,
    short* __restrict__ v_t, short* __restrict__ g_buf,
    float* __restrict__ nb2)
{
    __shared__ short wlds[2][8192];      // 2 x 16 KB weight chunk
    __shared__ short trans[4][32 * 72];  // per-wave transpose tile
    __shared__ float mu_s[128], rs_s[128];
    __shared__ float lnw_s[128], lnb_s[128], bg_s[128];

    const int tid = threadIdx.x;
    const int pbase = blockIdx.x * 128;
    const int i = pbase >> 8, jb = pbase & 255;

    if (tid < 128) {
        lnw_s[tid] = ln_w[tid]; lnb_s[tid] = ln_b[tid]; bg_s[tid] = bg[tid];
    }

    // LN stats: 2 threads per row
    {
        int m = tid >> 1, seg = tid & 1;
        const float* row = act + (size_t)(pbase + m) * 128 + seg * 64;
        float a = 0.f, b = 0.f;
        #pragma unroll
        for (int j = 0; j < 16; ++j) {
            float4 t = *(const float4*)(row + j * 4);
            a += t.x + t.y + t.z + t.w;
            b += t.x * t.x + t.y * t.y + t.z * t.z + t.w * t.w;
        }
        a += __shfl_xor(a, 1); b += __shfl_xor(b, 1);
        if (!seg) {
            float mu = a * (1.f / 128.f);
            float var = b * (1.f / 128.f) - mu * mu;
            mu_s[m] = mu; rs_s[m] = rsqrtf(var + LN_EPS);
        }
    }
    __syncthreads();

    const int w = tid >> 6, l = tid & 63, lr = l & 15, lh = l >> 4;
    const int wbase = w * 32, P0 = pbase + wbase;

    // A fragments (LN applied on the fly)
    bf16x8 af[2][4];
    #pragma unroll
    for (int qt = 0; qt < 2; ++qt) {
        int lrow = wbase + qt * 16 + lr;
        float mu = mu_s[lrow], rs = rs_s[lrow];
        const float* rowp = act + (size_t)(pbase + lrow) * 128 + lh * 8;
        #pragma unroll
        for (int kc = 0; kc < 4; ++kc) {
            float4 a = *(const float4*)(rowp + kc * 32);
            float4 b = *(const float4*)(rowp + kc * 32 + 4);
            int c0 = kc * 32 + lh * 8;
            bf16x8 f;
            f[0] = f2bf((a.x - mu) * rs * lnw_s[c0 + 0] + lnb_s[c0 + 0]);
            f[1] = f2bf((a.y - mu) * rs * lnw_s[c0 + 1] + lnb_s[c0 + 1]);
            f[2] = f2bf((a.z - mu) * rs * lnw_s[c0 + 2] + lnb_s[c0 + 2]);
            f[3] = f2bf((a.w - mu) * rs * lnw_s[c0 + 3] + lnb_s[c0 + 3]);
            f[4] = f2bf((b.x - mu) * rs * lnw_s[c0 + 4] + lnb_s[c0 + 4]);
            f[5] = f2bf((b.y - mu) * rs * lnw_s[c0 + 5] + lnb_s[c0 + 5]);
            f[6] = f2bf((b.z - mu) * rs * lnw_s[c0 + 6] + lnb_s[c0 + 6]);
            f[7] = f2bf((b.w - mu) * rs * lnw_s[c0 + 7] + lnb_s[c0 + 7]);
            af[qt][kc] = f;
        }
    }

    u32x4 stg[4];
    #define LOAD_STAGE(ct) { \
        _Pragma("unroll") \
        for (int j = 0; j < 4; ++j) { \
            int D = j * 4096 + tid * 16; \
            int col = D >> 8, sp = (D >> 4) & 15; \
            int s = sp ^ (col & 15); \
            stg[j] = *(const u32x4*)(wT + (ct) * 8192 + col * 128 + s * 8); \
        } }
    #define WRITE_STAGE(b) { \
        _Pragma("unroll") \
        for (int j = 0; j < 4; ++j) \
            *(u32x4*)&wlds[b][j * 2048 + tid * 8] = stg[j]; }

    LOAD_STAGE(0);
    WRITE_STAGE(0);
    __syncthreads();

    f32x4 z = {0.f, 0.f, 0.f, 0.f};
    for (int ct = 0; ct < 8; ++ct) {
        if (ct < 7) LOAD_STAGE(ct + 1);

        const short* wb = wlds[ct & 1];
        f32x4 acc[2][4];
        #pragma unroll
        for (int ctile = 0; ctile < 4; ++ctile) { acc[0][ctile] = z; acc[1][ctile] = z; }
        #pragma unroll
        for (int kc = 0; kc < 4; ++kc) {
            #pragma unroll
            for (int ctile = 0; ctile < 4; ++ctile) {
                int col = ctile * 16 + lr;
                bf16x8 b = *(const bf16x8*)&wb[col * 128 + (((kc * 4 + lh) ^ lr) * 8)];
                acc[0][ctile] = __builtin_amdgcn_mfma_f32_16x16x32_bf16(af[0][kc], b, acc[0][ctile], 0, 0, 0);
                acc[1][ctile] = __builtin_amdgcn_mfma_f32_16x16x32_bf16(af[1][kc], b, acc[1][ctile], 0, 0, 0);
            }
        }

        const int mat = ct >> 1, half = ct & 1;
        if (mat == 2) {
            #pragma unroll
            for (int qt = 0; qt < 2; ++qt)
                #pragma unroll
                for (int ctile = 0; ctile < 4; ++ctile) {
                    int chan = half * 64 + ctile * 16 + lr;
                    unsigned p0, p1;
                    asm("v_cvt_pk_bf16_f32 %0, %1, %2" : "=v"(p0)
                        : "v"(acc[qt][ctile][0]), "v"(acc[qt][ctile][1]));
                    asm("v_cvt_pk_bf16_f32 %0, %1, %2" : "=v"(p1)
                        : "v"(acc[qt][ctile][2]), "v"(acc[qt][ctile][3]));
                    uint2 st = { p0, p1 };
                    *(uint2*)(v_t + ((size_t)i * 128 + chan) * 256 + jb + wbase
                              + qt * 16 + lh * 4) = st;
                }
        } else {
            short* tw = &trans[w][0];
            #pragma unroll
            for (int qt = 0; qt < 2; ++qt)
                #pragma unroll
                for (int ctile = 0; ctile < 4; ++ctile) {
                    int col = ctile * 16 + lr;
                    if (mat == 3) {
                        float bgv = bg_s[half * 64 + col];
                        #pragma unroll
                        for (int r = 0; r < 4; ++r) {
                            float v = acc[qt][ctile][r] + bgv;
                            v = __builtin_amdgcn_rcpf(1.f + __builtin_amdgcn_exp2f(-v * LOG2E));
                            tw[(qt * 16 + lh * 4 + r) * 72 + col] = f2bf(v);
                        }
                    } else {
                        #pragma unroll
                        for (int r = 0; r < 4; ++r)
                            tw[(qt * 16 + lh * 4 + r) * 72 + col] = f2bf(acc[qt][ctile][r]);
                    }
                }
            short* G = (mat == 0) ? q_buf : (mat == 1) ? k_buf : g_buf;
            short* dst = G + (size_t)(P0 + (l >> 1)) * 128 + half * 64 + (l & 1) * 32;
            const short* src = tw + (l >> 1) * 72 + (l & 1) * 32;
            #pragma unroll
            for (int j = 0; j < 4; ++j)
                *(u32x4*)(dst + j * 8) = *(const u32x4*)(src + j * 8);
        }

        if (ct < 7) WRITE_STAGE((ct + 1) & 1);
        __syncthreads();
    }

    // w2d chunk -> nb2[h][q*256+k] flat-position f32x4 store (R9 verbatim)
    {
        const short* w2 = wT + 5 * 16384 + lr * 128 + lh * 8;
        f32x4 acc0 = z, acc1 = z;
        #pragma unroll
        for (int kc = 0; kc < 4; ++kc) {
            bf16x8 b = *(const bf16x8*)(w2 + kc * 32);
            acc0 = __builtin_amdgcn_mfma_f32_16x16x32_bf16(af[0][kc], b, acc0, 0, 0, 0);
            acc1 = __builtin_amdgcn_mfma_f32_16x16x32_bf16(af[1][kc], b, acc1, 0, 0, 0);
        }
        if (lr < 4) {
            *(f32x4*)(nb2 + (size_t)lr * 65536 + P0 + lh * 4)      = acc0;
            *(f32x4*)(nb2 + (size_t)lr * 65536 + P0 + 16 + lh * 4) = acc1;
        }
    }
}

// ---------------------------------------------------------------------------
// Kernel 1.5: nb layout transpose. nb2[h][q*256+k] -> nb4[h][(q>>2)*1024
// + k*4 + (q&3)]. 262,144 dest floats / 4 per thread = 65,536 threads =
// 256 blocks x 256 thr. (R14 bug: launched 1024 blocks -> 3MB overrun
// clobbered wT. Fixed: 256 blocks + explicit guard.)
// ---------------------------------------------------------------------------
__global__ __launch_bounds__(256) void nbt_kernel(
    const float* __restrict__ nb2, float* __restrict__ nb4)
{
    int gid = blockIdx.x * 256 + threadIdx.x;   // 0..65535
    if (gid >= 65536) return;
    int d0 = gid * 4;                            // dest float index
    int h = d0 >> 16;
    int rem = d0 & 65535;
    int qhi = rem >> 10, r2 = rem & 1023, k = r2 >> 2;
    const float* src = nb2 + ((size_t)h << 16) + (size_t)(qhi * 4) * 256 + k;
    f32x4 v = { src[0], src[256], src[512], src[768] };
    *(f32x4*)(nb4 + d0) = v;
}

// ---------------------------------------------------------------------------
// Kernel 2: attention. R13-verbatim (1024 blocks (i,h), 256 thr, wave = 64
// queries; nb read as coalesced f32x4 from nb4, added post-MFMA in VALU).
// ---------------------------------------------------------------------------
__global__ __launch_bounds__(256) void attn_kernel(
    const float* __restrict__ mask,
    const short* __restrict__ q_buf, const short* __restrict__ k_buf,
    const short* __restrict__ v_t, const short* __restrict__ g_buf,
    const float* __restrict__ nb4, short* __restrict__ og_buf)
{
    __shared__ unsigned p_lds[4][64 * 20];
    __shared__ float bias_s[256];

    const int tid = threadIdx.x, bid = blockIdx.x;
    const int i = bid >> 2, h = bid & 3;

    bias_s[tid] = 1e9f * (mask[i * 256 + tid] - 1.f) * LOG2E;
    __syncthreads();

    const int w = tid >> 6, l = tid & 63, lr = l & 15, lh = l >> 4;
    const int qbase = w * 64;

    const short* qrow = q_buf + ((size_t)(i * 256 + qbase)) * 128 + h * 32;
    bf16x8 qf[4];
    #pragma unroll
    for (int qt = 0; qt < 4; ++qt)
        qf[qt] = *(const bf16x8*)(qrow + (qt * 16 + lr) * 128 + lh * 8);

    const short* krow = k_buf + ((size_t)(i * 256)) * 128 + h * 32 + lh * 8;
    const short* vrow = v_t + ((size_t)i * 128 + h * 32) * 256;
    const float* nbbase = nb4 + (size_t)h * 65536 + (size_t)(qbase >> 2) * 1024;
    unsigned* pw = &p_lds[w][0];

    f32x4 z = {0.f, 0.f, 0.f, 0.f};
    f32x4 o[4][2];
    float lsum[4][4];
    #pragma unroll
    for (int qt = 0; qt < 4; ++qt) {
        o[qt][0] = z; o[qt][1] = z;
        #pragma unroll
        for (int r = 0; r < 4; ++r) lsum[qt][r] = 0.f;
    }

    for (int kk = 0; kk < 256; kk += 32) {
        bf16x8 bk0 = *(const bf16x8*)(krow + (size_t)(kk + lr) * 128);
        bf16x8 bk1 = *(const bf16x8*)(krow + (size_t)(kk + 16 + lr) * 128);
        float b0 = bias_s[kk + lr], b1 = bias_s[kk + 16 + lr];
        #pragma unroll
        for (int qt = 0; qt < 4; ++qt) {
            const float* nbr = nbbase + (size_t)(qt * 4 + lh) * 1024 + (kk + lr) * 4;
            f32x4 cnb0 = *(const f32x4*)(nbr);
            f32x4 cnb1 = *(const f32x4*)(nbr + 64);   // k + 16
            f32x4 s0 = __builtin_amdgcn_mfma_f32_16x16x32_bf16(qf[qt], bk0, z, 0, 0, 0);
            f32x4 s1 = __builtin_amdgcn_mfma_f32_16x16x32_bf16(qf[qt], bk1, z, 0, 0, 0);
            #pragma unroll
            for (int r = 0; r < 4; ++r) {
                float p0 = __builtin_amdgcn_exp2f(s0[r] + b0 + cnb0[r]);
                float p1 = __builtin_amdgcn_exp2f(s1[r] + b1 + cnb1[r]);
                lsum[qt][r] += p0 + p1;
                unsigned pk;
                asm("v_cvt_pk_bf16_f32 %0, %1, %2" : "=v"(pk) : "v"(p0), "v"(p1));
                pw[(qt * 16 + lh * 4 + r) * 20 + lr] = pk;
            }
        }
        const short* vb = vrow + kk + lh * 4;
        uint2 a0 = *(const uint2*)(vb + (size_t)lr * 256);
        uint2 c0 = *(const uint2*)(vb + (size_t)lr * 256 + 16);
        uint2 a1 = *(const uint2*)(vb + (size_t)(16 + lr) * 256);
        uint2 c1 = *(const uint2*)(vb + (size_t)(16 + lr) * 256 + 16);
        u32x4 u0 = { __builtin_amdgcn_perm(c0.x, a0.x, 0x05040100),
                     __builtin_amdgcn_perm(c0.x, a0.x, 0x07060302),
                     __builtin_amdgcn_perm(c0.y, a0.y, 0x05040100),
                     __builtin_amdgcn_perm(c0.y, a0.y, 0x07060302) };
        u32x4 u1 = { __builtin_amdgcn_perm(c1.x, a1.x, 0x05040100),
                     __builtin_amdgcn_perm(c1.x, a1.x, 0x07060302),
                     __builtin_amdgcn_perm(c1.y, a1.y, 0x05040100),
                     __builtin_amdgcn_perm(c1.y, a1.y, 0x07060302) };
        bf16x8 bv0 = __builtin_bit_cast(bf16x8, u0);
        bf16x8 bv1 = __builtin_bit_cast(bf16x8, u1);
        #pragma unroll
        for (int qt = 0; qt < 4; ++qt) {
            bf16x8 pa = *(const bf16x8*)(pw + (qt * 16 + lr) * 20 + lh * 4);
            o[qt][0] = __builtin_amdgcn_mfma_f32_16x16x32_bf16(pa, bv0, o[qt][0], 0, 0, 0);
            o[qt][1] = __builtin_amdgcn_mfma_f32_16x16x32_bf16(pa, bv1, o[qt][1], 0, 0, 0);
        }
    }

    float inv[4][4];
    #pragma unroll
    for (int qt = 0; qt < 4; ++qt)
        #pragma unroll
        for (int r = 0; r < 4; ++r) {
            float v = lsum[qt][r];
            v += __shfl_xor(v, 1); v += __shfl_xor(v, 2);
            v += __shfl_xor(v, 4); v += __shfl_xor(v, 8);
            inv[qt][r] = __builtin_amdgcn_rcpf(v);
        }

    short* ow = (short*)pw;
    const short* grow = g_buf + ((size_t)(i * 256 + qbase)) * 128 + h * 32;
    #pragma unroll
    for (int qt = 0; qt < 4; ++qt)
        #pragma unroll
        for (int ct = 0; ct < 2; ++ct) {
            int c = ct * 16 + lr;
            #pragma unroll
            for (int r = 0; r < 4; ++r) {
                int q = qt * 16 + lh * 4 + r;
                float gf = bf2f((unsigned short)grow[(size_t)q * 128 + c]);
                ow[q * 40 + c] = f2bf(o[qt][ct][r] * inv[qt][r] * gf);
            }
        }
    short* og_row = og_buf + ((size_t)(i * 256 + qbase)) * 128 + h * 32;
    #pragma unroll
    for (int j = 0; j < 4; ++j) {
        u32x4 t = *(const u32x4*)(ow + l * 40 + j * 8);
        *(u32x4*)(og_row + (size_t)l * 128 + j * 8) = t;
    }
}

// ---------------------------------------------------------------------------
// Kernel 3: output projection. 1024 blocks (64 pos), 256 thr.
// ---------------------------------------------------------------------------
__global__ __launch_bounds__(256) void out_kernel(
    const short* __restrict__ og_buf, const short* __restrict__ wT,
    const float* __restrict__ bo, float* __restrict__ out)
{
    const int tid = threadIdx.x;
    const int pbase = blockIdx.x * 64;
    const int w = tid >> 6, l = tid & 63, lr = l & 15, lh = l >> 4;

    bf16x8 af[4][4];
    #pragma unroll
    for (int qt = 0; qt < 4; ++qt) {
        const short* rp = og_buf + (size_t)(pbase + qt * 16 + lr) * 128 + lh * 8;
        #pragma unroll
        for (int kc = 0; kc < 4; ++kc) af[qt][kc] = *(const bf16x8*)(rp + kc * 32);
    }
    const short* wo_t = wT + 4 * 16384;
    f32x4 z = {0.f, 0.f, 0.f, 0.f};
    #pragma unroll
    for (int ct = 0; ct < 2; ++ct) {
        int col = w * 32 + ct * 16 + lr;
        f32x4 acc0 = z, acc1 = z, acc2 = z, acc3 = z;
        #pragma unroll
        for (int kc = 0; kc < 4; ++kc) {
            bf16x8 b = *(const bf16x8*)(wo_t + col * 128 + kc * 32 + lh * 8);
            acc0 = __builtin_amdgcn_mfma_f32_16x16x32_bf16(af[0][kc], b, acc0, 0, 0, 0);
            acc1 = __builtin_amdgcn_mfma_f32_16x16x32_bf16(af[1][kc], b, acc1, 0, 0, 0);
            acc2 = __builtin_amdgcn_mfma_f32_16x16x32_bf16(af[2][kc], b, acc2, 0, 0, 0);
            acc3 = __builtin_amdgcn_mfma_f32_16x16x32_bf16(af[3][kc], b, acc3, 0, 0, 0);
        }
        f32x4 acc[4] = {acc0, acc1, acc2, acc3};
        float bov = bo[col];
        #pragma unroll
        for (int qt = 0; qt < 4; ++qt)
            #pragma unroll
            for (int r = 0; r < 4; ++r)
                out[(size_t)(pbase + qt * 16 + lh * 4 + r) * 128 + col] =
                    acc[qt][r] + bov;
    }
}

// ---------------------------------------------------------------------------
extern "C" void kernel_launch(void* const* d_in, const int* in_sizes, int n_in,
                              void* d_out, int out_size, void* d_ws, size_t ws_size,
                              hipStream_t stream) {
    const float* act  = (const float*)d_in[0];
    const float* mask = (const float*)d_in[1];
    const float* ln_w = (const float*)d_in[2];
    const float* ln_b = (const float*)d_in[3];
    const float* w2d  = (const float*)d_in[4];
    const float* wq   = (const float*)d_in[5];
    const float* wk   = (const float*)d_in[6];
    const float* wv   = (const float*)d_in[7];
    const float* wg   = (const float*)d_in[8];
    const float* bg   = (const float*)d_in[9];
    const float* wo   = (const float*)d_in[10];
    const float* bo   = (const float*)d_in[11];
    float* out = (float*)d_out;

    char* ws = (char*)d_ws;
    short* q_buf  = (short*)(ws);
    short* k_buf  = (short*)(ws + 16777216);
    short* v_t    = (short*)(ws + 2 * 16777216);
    short* og_buf = (short*)(ws + 3 * 16777216);
    short* g_buf  = (short*)(ws + 4 * 16777216);
    float* nb2    = (float*)(ws + 5 * 16777216);
    float* nb4    = (float*)(ws + 5 * 16777216 + 1048576);
    short* wT     = (short*)(ws + 5 * 16777216 + 2 * 1048576);

    prep_kernel<<<328, 256, 0, stream>>>(wq, wk, wv, wg, wo, w2d, wT);
    proj_kernel<<<512, 256, 0, stream>>>(act, ln_w, ln_b, bg, wT,
                                         q_buf, k_buf, v_t, g_buf, nb2);
    nbt_kernel<<<256, 256, 0, stream>>>(nb2, nb4);
    attn_kernel<<<1024, 256, 0, stream>>>(mask, q_buf, k_buf, v_t, g_buf,
                                          nb4, og_buf);
    out_kernel<<<1024, 256, 0, stream>>>(og_buf, wT, bo, out);
}

// Round 16
// 105.473 us; speedup vs baseline: 1.0258x; 1.0258x over previous
//
#include <hip/hip_runtime.h>
#include <math.h>

#define LOG2E  1.4426950408889634f
#define LN_EPS 1e-5f

typedef __attribute__((ext_vector_type(8))) short bf16x8;
typedef __attribute__((ext_vector_type(4))) float f32x4;
typedef __attribute__((ext_vector_type(4))) unsigned u32x4;

__device__ __forceinline__ short f2bf(float x) {
    unsigned u = __builtin_bit_cast(unsigned, x);
    u = (u + 0x7FFF + ((u >> 16) & 1)) >> 16;
    return (short)u;
}
__device__ __forceinline__ float bf2f(unsigned short b) {
    return __builtin_bit_cast(float, (unsigned)b << 16);
}

// ---------------------------------------------------------------------------
// ws layout (bytes):
//  q_buf  bf16 [65536][128]      : 16,777,216
//  k_buf  bf16 [65536][128]      : 16,777,216
//  v_t    bf16 [256][128][256]   : 16,777,216   (V transposed per row i)
//  og_buf bf16 [65536][128]      : 16,777,216
//  g_buf  bf16 [65536][128]      : 16,777,216
//  nb4    f32  [4][65536]        :  1,048,576   ([h][(q>>2)*1024+k*4+(q&3)])
//  wT     bf16 5*16384+2048      :    167,936   ([mat][col][k]; +w2d tile)
// ---------------------------------------------------------------------------

__global__ __launch_bounds__(256) void prep_kernel(
    const float* __restrict__ wq, const float* __restrict__ wk,
    const float* __restrict__ wv, const float* __restrict__ wg,
    const float* __restrict__ wo, const float* __restrict__ w2d,
    short* __restrict__ wT)
{
    int gid = blockIdx.x * 256 + threadIdx.x;
    if (gid < 5 * 16384) {
        int m = gid >> 14, r = gid & 16383, col = r >> 7, k = r & 127;
        const float* W = (m == 0) ? wq : (m == 1) ? wk : (m == 2) ? wv
                       : (m == 3) ? wg : wo;
        float s = (m == 0) ? (0.17677669529663687f * LOG2E) : 1.0f;
        wT[gid] = f2bf(W[k * 128 + col] * s);
    } else if (gid < 5 * 16384 + 16 * 128) {
        int r = gid - 5 * 16384, col = r >> 7, k = r & 127;
        float v = (col < 4) ? w2d[k * 4 + col] * LOG2E : 0.0f;
        wT[gid] = f2bf(v);
    }
}

// ---------------------------------------------------------------------------
// Kernel 1: LN + projections. 512 blocks (128 positions), 256 thr (4 waves).
// Changes vs R15: (a) SINGLE-buffered 16 KB weight LDS (reg-staged prefetch
// kept; second barrier per chunk) -> LDS ~36.5 KB -> 4 blocks/CU (was 2);
// (b) w2d epilogue stores nb4 directly (R13's verified scatter) - no nbt.
// ---------------------------------------------------------------------------
__global__ __launch_bounds__(256) void proj_kernel(
    const float* __restrict__ act, const float* __restrict__ ln_w,
    const float* __restrict__ ln_b, const float* __restrict__ bg,
    const short* __restrict__ wT,
    short* __restrict__ q_buf, short* __restrict__ k_buf,
    short* __restrict__ v_t, short* __restrict__ g_buf,
    float* __restrict__ nb4)
{
    __shared__ short wlds[8192];         // ONE 16 KB weight chunk
    __shared__ short trans[4][32 * 72];  // per-wave transpose tile
    __shared__ float mu_s[128], rs_s[128];
    __shared__ float lnw_s[128], lnb_s[128], bg_s[128];

    const int tid = threadIdx.x;
    const int pbase = blockIdx.x * 128;
    const int i = pbase >> 8, jb = pbase & 255;

    if (tid < 128) {
        lnw_s[tid] = ln_w[tid]; lnb_s[tid] = ln_b[tid]; bg_s[tid] = bg[tid];
    }

    // LN stats: 2 threads per row
    {
        int m = tid >> 1, seg = tid & 1;
        const float* row = act + (size_t)(pbase + m) * 128 + seg * 64;
        float a = 0.f, b = 0.f;
        #pragma unroll
        for (int j = 0; j < 16; ++j) {
            float4 t = *(const float4*)(row + j * 4);
            a += t.x + t.y + t.z + t.w;
            b += t.x * t.x + t.y * t.y + t.z * t.z + t.w * t.w;
        }
        a += __shfl_xor(a, 1); b += __shfl_xor(b, 1);
        if (!seg) {
            float mu = a * (1.f / 128.f);
            float var = b * (1.f / 128.f) - mu * mu;
            mu_s[m] = mu; rs_s[m] = rsqrtf(var + LN_EPS);
        }
    }
    __syncthreads();

    const int w = tid >> 6, l = tid & 63, lr = l & 15, lh = l >> 4;
    const int wbase = w * 32, P0 = pbase + wbase;

    // A fragments (LN applied on the fly)
    bf16x8 af[2][4];
    #pragma unroll
    for (int qt = 0; qt < 2; ++qt) {
        int lrow = wbase + qt * 16 + lr;
        float mu = mu_s[lrow], rs = rs_s[lrow];
        const float* rowp = act + (size_t)(pbase + lrow) * 128 + lh * 8;
        #pragma unroll
        for (int kc = 0; kc < 4; ++kc) {
            float4 a = *(const float4*)(rowp + kc * 32);
            float4 b = *(const float4*)(rowp + kc * 32 + 4);
            int c0 = kc * 32 + lh * 8;
            bf16x8 f;
            f[0] = f2bf((a.x - mu) * rs * lnw_s[c0 + 0] + lnb_s[c0 + 0]);
            f[1] = f2bf((a.y - mu) * rs * lnw_s[c0 + 1] + lnb_s[c0 + 1]);
            f[2] = f2bf((a.z - mu) * rs * lnw_s[c0 + 2] + lnb_s[c0 + 2]);
            f[3] = f2bf((a.w - mu) * rs * lnw_s[c0 + 3] + lnb_s[c0 + 3]);
            f[4] = f2bf((b.x - mu) * rs * lnw_s[c0 + 4] + lnb_s[c0 + 4]);
            f[5] = f2bf((b.y - mu) * rs * lnw_s[c0 + 5] + lnb_s[c0 + 5]);
            f[6] = f2bf((b.z - mu) * rs * lnw_s[c0 + 6] + lnb_s[c0 + 6]);
            f[7] = f2bf((b.w - mu) * rs * lnw_s[c0 + 7] + lnb_s[c0 + 7]);
            af[qt][kc] = f;
        }
    }

    u32x4 stg[4];
    #define LOAD_STAGE(ct) { \
        _Pragma("unroll") \
        for (int j = 0; j < 4; ++j) { \
            int D = j * 4096 + tid * 16; \
            int col = D >> 8, sp = (D >> 4) & 15; \
            int s = sp ^ (col & 15); \
            stg[j] = *(const u32x4*)(wT + (ct) * 8192 + col * 128 + s * 8); \
        } }
    #define WRITE_STAGE() { \
        _Pragma("unroll") \
        for (int j = 0; j < 4; ++j) \
            *(u32x4*)&wlds[j * 2048 + tid * 8] = stg[j]; }

    LOAD_STAGE(0);
    WRITE_STAGE();
    __syncthreads();

    f32x4 z = {0.f, 0.f, 0.f, 0.f};
    for (int ct = 0; ct < 8; ++ct) {
        if (ct < 7) LOAD_STAGE(ct + 1);          // prefetch to regs (T14)

        const short* wb = wlds;
        f32x4 acc[2][4];
        #pragma unroll
        for (int ctile = 0; ctile < 4; ++ctile) { acc[0][ctile] = z; acc[1][ctile] = z; }
        #pragma unroll
        for (int kc = 0; kc < 4; ++kc) {
            #pragma unroll
            for (int ctile = 0; ctile < 4; ++ctile) {
                int col = ctile * 16 + lr;
                bf16x8 b = *(const bf16x8*)&wb[col * 128 + (((kc * 4 + lh) ^ lr) * 8)];
                acc[0][ctile] = __builtin_amdgcn_mfma_f32_16x16x32_bf16(af[0][kc], b, acc[0][ctile], 0, 0, 0);
                acc[1][ctile] = __builtin_amdgcn_mfma_f32_16x16x32_bf16(af[1][kc], b, acc[1][ctile], 0, 0, 0);
            }
        }

        const int mat = ct >> 1, half = ct & 1;
        if (mat == 2) {
            #pragma unroll
            for (int qt = 0; qt < 2; ++qt)
                #pragma unroll
                for (int ctile = 0; ctile < 4; ++ctile) {
                    int chan = half * 64 + ctile * 16 + lr;
                    unsigned p0, p1;
                    asm("v_cvt_pk_bf16_f32 %0, %1, %2" : "=v"(p0)
                        : "v"(acc[qt][ctile][0]), "v"(acc[qt][ctile][1]));
                    asm("v_cvt_pk_bf16_f32 %0, %1, %2" : "=v"(p1)
                        : "v"(acc[qt][ctile][2]), "v"(acc[qt][ctile][3]));
                    uint2 st = { p0, p1 };
                    *(uint2*)(v_t + ((size_t)i * 128 + chan) * 256 + jb + wbase
                              + qt * 16 + lh * 4) = st;
                }
        } else {
            short* tw = &trans[w][0];
            #pragma unroll
            for (int qt = 0; qt < 2; ++qt)
                #pragma unroll
                for (int ctile = 0; ctile < 4; ++ctile) {
                    int col = ctile * 16 + lr;
                    if (mat == 3) {
                        float bgv = bg_s[half * 64 + col];
                        #pragma unroll
                        for (int r = 0; r < 4; ++r) {
                            float v = acc[qt][ctile][r] + bgv;
                            v = __builtin_amdgcn_rcpf(1.f + __builtin_amdgcn_exp2f(-v * LOG2E));
                            tw[(qt * 16 + lh * 4 + r) * 72 + col] = f2bf(v);
                        }
                    } else {
                        #pragma unroll
                        for (int r = 0; r < 4; ++r)
                            tw[(qt * 16 + lh * 4 + r) * 72 + col] = f2bf(acc[qt][ctile][r]);
                    }
                }
            short* G = (mat == 0) ? q_buf : (mat == 1) ? k_buf : g_buf;
            short* dst = G + (size_t)(P0 + (l >> 1)) * 128 + half * 64 + (l & 1) * 32;
            const short* src = tw + (l >> 1) * 72 + (l & 1) * 32;
            #pragma unroll
            for (int j = 0; j < 4; ++j)
                *(u32x4*)(dst + j * 8) = *(const u32x4*)(src + j * 8);
        }

        __syncthreads();                          // all waves done reading wlds
        if (ct < 7) {
            WRITE_STAGE();                        // overwrite with next chunk
            __syncthreads();                      // writes visible
        }
    }

    // w2d chunk -> nb4[h][(q>>2)*1024 + k*4 + (q&3)], q=i, k=j (R13 verified)
    {
        const short* w2 = wT + 5 * 16384 + lr * 128 + lh * 8;
        f32x4 acc0 = z, acc1 = z;
        #pragma unroll
        for (int kc = 0; kc < 4; ++kc) {
            bf16x8 b = *(const bf16x8*)(w2 + kc * 32);
            acc0 = __builtin_amdgcn_mfma_f32_16x16x32_bf16(af[0][kc], b, acc0, 0, 0, 0);
            acc1 = __builtin_amdgcn_mfma_f32_16x16x32_bf16(af[1][kc], b, acc1, 0, 0, 0);
        }
        if (lr < 4) {
            const int kc0 = (P0 & 255) + lh * 4;
            float* nbh = nb4 + (size_t)lr * 65536
                       + (size_t)(i >> 2) * 1024 + (i & 3);
            #pragma unroll
            for (int r = 0; r < 4; ++r) {
                nbh[(kc0 + r) * 4]      = acc0[r];
                nbh[(kc0 + 16 + r) * 4] = acc1[r];
            }
        }
    }
}

// ---------------------------------------------------------------------------
// Kernel 2: attention. R13/R15-verbatim (1024 blocks (i,h), 256 thr, wave =
// 64 queries; nb read as coalesced f32x4 from nb4, added post-MFMA in VALU).
// ---------------------------------------------------------------------------
__global__ __launch_bounds__(256) void attn_kernel(
    const float* __restrict__ mask,
    const short* __restrict__ q_buf, const short* __restrict__ k_buf,
    const short* __restrict__ v_t, const short* __restrict__ g_buf,
    const float* __restrict__ nb4, short* __restrict__ og_buf)
{
    __shared__ unsigned p_lds[4][64 * 20];
    __shared__ float bias_s[256];

    const int tid = threadIdx.x, bid = blockIdx.x;
    const int i = bid >> 2, h = bid & 3;

    bias_s[tid] = 1e9f * (mask[i * 256 + tid] - 1.f) * LOG2E;
    __syncthreads();

    const int w = tid >> 6, l = tid & 63, lr = l & 15, lh = l >> 4;
    const int qbase = w * 64;

    const short* qrow = q_buf + ((size_t)(i * 256 + qbase)) * 128 + h * 32;
    bf16x8 qf[4];
    #pragma unroll
    for (int qt = 0; qt < 4; ++qt)
        qf[qt] = *(const bf16x8*)(qrow + (qt * 16 + lr) * 128 + lh * 8);

    const short* krow = k_buf + ((size_t)(i * 256)) * 128 + h * 32 + lh * 8;
    const short* vrow = v_t + ((size_t)i * 128 + h * 32) * 256;
    const float* nbbase = nb4 + (size_t)h * 65536 + (size_t)(qbase >> 2) * 1024;
    unsigned* pw = &p_lds[w][0];

    f32x4 z = {0.f, 0.f, 0.f, 0.f};
    f32x4 o[4][2];
    float lsum[4][4];
    #pragma unroll
    for (int qt = 0; qt < 4; ++qt) {
        o[qt][0] = z; o[qt][1] = z;
        #pragma unroll
        for (int r = 0; r < 4; ++r) lsum[qt][r] = 0.f;
    }

    for (int kk = 0; kk < 256; kk += 32) {
        bf16x8 bk0 = *(const bf16x8*)(krow + (size_t)(kk + lr) * 128);
        bf16x8 bk1 = *(const bf16x8*)(krow + (size_t)(kk + 16 + lr) * 128);
        float b0 = bias_s[kk + lr], b1 = bias_s[kk + 16 + lr];
        #pragma unroll
        for (int qt = 0; qt < 4; ++qt) {
            const float* nbr = nbbase + (size_t)(qt * 4 + lh) * 1024 + (kk + lr) * 4;
            f32x4 cnb0 = *(const f32x4*)(nbr);
            f32x4 cnb1 = *(const f32x4*)(nbr + 64);   // k + 16
            f32x4 s0 = __builtin_amdgcn_mfma_f32_16x16x32_bf16(qf[qt], bk0, z, 0, 0, 0);
            f32x4 s1 = __builtin_amdgcn_mfma_f32_16x16x32_bf16(qf[qt], bk1, z, 0, 0, 0);
            #pragma unroll
            for (int r = 0; r < 4; ++r) {
                float p0 = __builtin_amdgcn_exp2f(s0[r] + b0 + cnb0[r]);
                float p1 = __builtin_amdgcn_exp2f(s1[r] + b1 + cnb1[r]);
                lsum[qt][r] += p0 + p1;
                unsigned pk;
                asm("v_cvt_pk_bf16_f32 %0, %1, %2" : "=v"(pk) : "v"(p0), "v"(p1));
                pw[(qt * 16 + lh * 4 + r) * 20 + lr] = pk;
            }
        }
        const short* vb = vrow + kk + lh * 4;
        uint2 a0 = *(const uint2*)(vb + (size_t)lr * 256);
        uint2 c0 = *(const uint2*)(vb + (size_t)lr * 256 + 16);
        uint2 a1 = *(const uint2*)(vb + (size_t)(16 + lr) * 256);
        uint2 c1 = *(const uint2*)(vb + (size_t)(16 + lr) * 256 + 16);
        u32x4 u0 = { __builtin_amdgcn_perm(c0.x, a0.x, 0x05040100),
                     __builtin_amdgcn_perm(c0.x, a0.x, 0x07060302),
                     __builtin_amdgcn_perm(c0.y, a0.y, 0x05040100),
                     __builtin_amdgcn_perm(c0.y, a0.y, 0x07060302) };
        u32x4 u1 = { __builtin_amdgcn_perm(c1.x, a1.x, 0x05040100),
                     __builtin_amdgcn_perm(c1.x, a1.x, 0x07060302),
                     __builtin_amdgcn_perm(c1.y, a1.y, 0x05040100),
                     __builtin_amdgcn_perm(c1.y, a1.y, 0x07060302) };
        bf16x8 bv0 = __builtin_bit_cast(bf16x8, u0);
        bf16x8 bv1 = __builtin_bit_cast(bf16x8, u1);
        #pragma unroll
        for (int qt = 0; qt < 4; ++qt) {
            bf16x8 pa = *(const bf16x8*)(pw + (qt * 16 + lr) * 20 + lh * 4);
            o[qt][0] = __builtin_amdgcn_mfma_f32_16x16x32_bf16(pa, bv0, o[qt][0], 0, 0, 0);
            o[qt][1] = __builtin_amdgcn_mfma_f32_16x16x32_bf16(pa, bv1, o[qt][1], 0, 0, 0);
        }
    }

    float inv[4][4];
    #pragma unroll
    for (int qt = 0; qt < 4; ++qt)
        #pragma unroll
        for (int r = 0; r < 4; ++r) {
            float v = lsum[qt][r];
            v += __shfl_xor(v, 1); v += __shfl_xor(v, 2);
            v += __shfl_xor(v, 4); v += __shfl_xor(v, 8);
            inv[qt][r] = __builtin_amdgcn_rcpf(v);
        }

    short* ow = (short*)pw;
    const short* grow = g_buf + ((size_t)(i * 256 + qbase)) * 128 + h * 32;
    #pragma unroll
    for (int qt = 0; qt < 4; ++qt)
        #pragma unroll
        for (int ct = 0; ct < 2; ++ct) {
            int c = ct * 16 + lr;
            #pragma unroll
            for (int r = 0; r < 4; ++r) {
                int q = qt * 16 + lh * 4 + r;
                float gf = bf2f((unsigned short)grow[(size_t)q * 128 + c]);
                ow[q * 40 + c] = f2bf(o[qt][ct][r] * inv[qt][r] * gf);
            }
        }
    short* og_row = og_buf + ((size_t)(i * 256 + qbase)) * 128 + h * 32;
    #pragma unroll
    for (int j = 0; j < 4; ++j) {
        u32x4 t = *(const u32x4*)(ow + l * 40 + j * 8);
        *(u32x4*)(og_row + (size_t)l * 128 + j * 8) = t;
    }
}

// ---------------------------------------------------------------------------
// Kernel 3: output projection. 1024 blocks (64 pos), 256 thr.
// ---------------------------------------------------------------------------
__global__ __launch_bounds__(256) void out_kernel(
    const short* __restrict__ og_buf, const short* __restrict__ wT,
    const float* __restrict__ bo, float* __restrict__ out)
{
    const int tid = threadIdx.x;
    const int pbase = blockIdx.x * 64;
    const int w = tid >> 6, l = tid & 63, lr = l & 15, lh = l >> 4;

    bf16x8 af[4][4];
    #pragma unroll
    for (int qt = 0; qt < 4; ++qt) {
        const short* rp = og_buf + (size_t)(pbase + qt * 16 + lr) * 128 + lh * 8;
        #pragma unroll
        for (int kc = 0; kc < 4; ++kc) af[qt][kc] = *(const bf16x8*)(rp + kc * 32);
    }
    const short* wo_t = wT + 4 * 16384;
    f32x4 z = {0.f, 0.f, 0.f, 0.f};
    #pragma unroll
    for (int ct = 0; ct < 2; ++ct) {
        int col = w * 32 + ct * 16 + lr;
        f32x4 acc0 = z, acc1 = z, acc2 = z, acc3 = z;
        #pragma unroll
        for (int kc = 0; kc < 4; ++kc) {
            bf16x8 b = *(const bf16x8*)(wo_t + col * 128 + kc * 32 + lh * 8);
            acc0 = __builtin_amdgcn_mfma_f32_16x16x32_bf16(af[0][kc], b, acc0, 0, 0, 0);
            acc1 = __builtin_amdgcn_mfma_f32_16x16x32_bf16(af[1][kc], b, acc1, 0, 0, 0);
            acc2 = __builtin_amdgcn_mfma_f32_16x16x32_bf16(af[2][kc], b, acc2, 0, 0, 0);
            acc3 = __builtin_amdgcn_mfma_f32_16x16x32_bf16(af[3][kc], b, acc3, 0, 0, 0);
        }
        f32x4 acc[4] = {acc0, acc1, acc2, acc3};
        float bov = bo[col];
        #pragma unroll
        for (int qt = 0; qt < 4; ++qt)
            #pragma unroll
            for (int r = 0; r < 4; ++r)
                out[(size_t)(pbase + qt * 16 + lh * 4 + r) * 128 + col] =
                    acc[qt][r] + bov;
    }
}

// ---------------------------------------------------------------------------
extern "C" void kernel_launch(void* const* d_in, const int* in_sizes, int n_in,
                              void* d_out, int out_size, void* d_ws, size_t ws_size,
                              hipStream_t stream) {
    const float* act  = (const float*)d_in[0];
    const float* mask = (const float*)d_in[1];
    const float* ln_w = (const float*)d_in[2];
    const float* ln_b = (const float*)d_in[3];
    const float* w2d  = (const float*)d_in[4];
    const float* wq   = (const float*)d_in[5];
    const float* wk   = (const float*)d_in[6];
    const float* wv   = (const float*)d_in[7];
    const float* wg   = (const float*)d_in[8];
    const float* bg   = (const float*)d_in[9];
    const float* wo   = (const float*)d_in[10];
    const float* bo   = (const float*)d_in[11];
    float* out = (float*)d_out;

    char* ws = (char*)d_ws;
    short* q_buf  = (short*)(ws);
    short* k_buf  = (short*)(ws + 16777216);
    short* v_t    = (short*)(ws + 2 * 16777216);
    short* og_buf = (short*)(ws + 3 * 16777216);
    short* g_buf  = (short*)(ws + 4 * 16777216);
    float* nb4    = (float*)(ws + 5 * 16777216);
    short* wT     = (short*)(ws + 5 * 16777216 + 1048576);

    prep_kernel<<<328, 256, 0, stream>>>(wq, wk, wv, wg, wo, w2d, wT);
    proj_kernel<<<512, 256, 0, stream>>>(act, ln_w, ln_b, bg, wT,
                                         q_buf, k_buf, v_t, g_buf, nb4);
    attn_kernel<<<1024, 256, 0, stream>>>(mask, q_buf, k_buf, v_t, g_buf,
                                          nb4, og_buf);
    out_kernel<<<1024, 256, 0, stream>>>(og_buf, wT, bo, out);
}

// Round 19
// 103.172 us; speedup vs baseline: 1.0487x; 1.0223x over previous
//
#include <hip/hip_runtime.h>
#include <math.h>

#define LOG2E  1.4426950408889634f
#define LN_EPS 1e-5f

typedef __attribute__((ext_vector_type(8))) short bf16x8;
typedef __attribute__((ext_vector_type(4))) float f32x4;
typedef __attribute__((ext_vector_type(4))) unsigned u32x4;

__device__ __forceinline__ short f2bf(float x) {
    unsigned u = __builtin_bit_cast(unsigned, x);
    u = (u + 0x7FFF + ((u >> 16) & 1)) >> 16;
    return (short)u;
}
__device__ __forceinline__ float bf2f(unsigned short b) {
    return __builtin_bit_cast(float, (unsigned)b << 16);
}

// ---------------------------------------------------------------------------
// ws layout (bytes):
//  q_buf  bf16 [65536][128]      : 16,777,216
//  k_buf  bf16 [65536][128]      : 16,777,216
//  v_t    bf16 [256][128][256]   : 16,777,216   (V transposed per row i)
//  og_buf bf16 [65536][128]      : 16,777,216
//  g_buf  bf16 [65536][128]      : 16,777,216
//  nb4    f32  [4][65536]        :  1,048,576   ([h][(q>>2)*1024+k*4+(q&3)])
//  wT     bf16 5*16384+2048      :    167,936   ([mat][col][k]; +w2d tile)
// ---------------------------------------------------------------------------

__global__ __launch_bounds__(256) void prep_kernel(
    const float* __restrict__ wq, const float* __restrict__ wk,
    const float* __restrict__ wv, const float* __restrict__ wg,
    const float* __restrict__ wo, const float* __restrict__ w2d,
    short* __restrict__ wT)
{
    int gid = blockIdx.x * 256 + threadIdx.x;
    if (gid < 5 * 16384) {
        int m = gid >> 14, r = gid & 16383, col = r >> 7, k = r & 127;
        const float* W = (m == 0) ? wq : (m == 1) ? wk : (m == 2) ? wv
                       : (m == 3) ? wg : wo;
        float s = (m == 0) ? (0.17677669529663687f * LOG2E) : 1.0f;
        wT[gid] = f2bf(W[k * 128 + col] * s);
    } else if (gid < 5 * 16384 + 16 * 128) {
        int r = gid - 5 * 16384, col = r >> 7, k = r & 127;
        float v = (col < 4) ? w2d[k * 4 + col] * LOG2E : 0.0f;
        wT[gid] = f2bf(v);
    }
}

// ---------------------------------------------------------------------------
// Kernel 1: LN + projections. 512 blocks (128 positions), 256 thr (4 waves).
// Single-buffered 16 KB weight LDS (reg-staged prefetch; second barrier per
// chunk); w2d epilogue stores nb4 directly (R13-verified scatter).
// ---------------------------------------------------------------------------
__global__ __launch_bounds__(256) void proj_kernel(
    const float* __restrict__ act, const float* __restrict__ ln_w,
    const float* __restrict__ ln_b, const float* __restrict__ bg,
    const short* __restrict__ wT,
    short* __restrict__ q_buf, short* __restrict__ k_buf,
    short* __restrict__ v_t, short* __restrict__ g_buf,
    float* __restrict__ nb4)
{
    __shared__ short wlds[8192];         // ONE 16 KB weight chunk
    __shared__ short trans[4][32 * 72];  // per-wave transpose tile
    __shared__ float mu_s[128], rs_s[128];
    __shared__ float lnw_s[128], lnb_s[128], bg_s[128];

    const int tid = threadIdx.x;
    const int pbase = blockIdx.x * 128;
    const int i = pbase >> 8, jb = pbase & 255;

    if (tid < 128) {
        lnw_s[tid] = ln_w[tid]; lnb_s[tid] = ln_b[tid]; bg_s[tid] = bg[tid];
    }

    // LN stats: 2 threads per row
    {
        int m = tid >> 1, seg = tid & 1;
        const float* row = act + (size_t)(pbase + m) * 128 + seg * 64;
        float a = 0.f, b = 0.f;
        #pragma unroll
        for (int j = 0; j < 16; ++j) {
            float4 t = *(const float4*)(row + j * 4);
            a += t.x + t.y + t.z + t.w;
            b += t.x * t.x + t.y * t.y + t.z * t.z + t.w * t.w;
        }
        a += __shfl_xor(a, 1); b += __shfl_xor(b, 1);
        if (!seg) {
            float mu = a * (1.f / 128.f);
            float var = b * (1.f / 128.f) - mu * mu;
            mu_s[m] = mu; rs_s[m] = rsqrtf(var + LN_EPS);
        }
    }
    __syncthreads();

    const int w = tid >> 6, l = tid & 63, lr = l & 15, lh = l >> 4;
    const int wbase = w * 32, P0 = pbase + wbase;

    // A fragments (LN applied on the fly)
    bf16x8 af[2][4];
    #pragma unroll
    for (int qt = 0; qt < 2; ++qt) {
        int lrow = wbase + qt * 16 + lr;
        float mu = mu_s[lrow], rs = rs_s[lrow];
        const float* rowp = act + (size_t)(pbase + lrow) * 128 + lh * 8;
        #pragma unroll
        for (int kc = 0; kc < 4; ++kc) {
            float4 a = *(const float4*)(rowp + kc * 32);
            float4 b = *(const float4*)(rowp + kc * 32 + 4);
            int c0 = kc * 32 + lh * 8;
            bf16x8 f;
            f[0] = f2bf((a.x - mu) * rs * lnw_s[c0 + 0] + lnb_s[c0 + 0]);
            f[1] = f2bf((a.y - mu) * rs * lnw_s[c0 + 1] + lnb_s[c0 + 1]);
            f[2] = f2bf((a.z - mu) * rs * lnw_s[c0 + 2] + lnb_s[c0 + 2]);
            f[3] = f2bf((a.w - mu) * rs * lnw_s[c0 + 3] + lnb_s[c0 + 3]);
            f[4] = f2bf((b.x - mu) * rs * lnw_s[c0 + 4] + lnb_s[c0 + 4]);
            f[5] = f2bf((b.y - mu) * rs * lnw_s[c0 + 5] + lnb_s[c0 + 5]);
            f[6] = f2bf((b.z - mu) * rs * lnw_s[c0 + 6] + lnb_s[c0 + 6]);
            f[7] = f2bf((b.w - mu) * rs * lnw_s[c0 + 7] + lnb_s[c0 + 7]);
            af[qt][kc] = f;
        }
    }

    u32x4 stg[4];
    #define LOAD_STAGE(ct) { \
        _Pragma("unroll") \
        for (int j = 0; j < 4; ++j) { \
            int D = j * 4096 + tid * 16; \
            int col = D >> 8, sp = (D >> 4) & 15; \
            int s = sp ^ (col & 15); \
            stg[j] = *(const u32x4*)(wT + (ct) * 8192 + col * 128 + s * 8); \
        } }
    #define WRITE_STAGE() { \
        _Pragma("unroll") \
        for (int j = 0; j < 4; ++j) \
            *(u32x4*)&wlds[j * 2048 + tid * 8] = stg[j]; }

    LOAD_STAGE(0);
    WRITE_STAGE();
    __syncthreads();

    f32x4 z = {0.f, 0.f, 0.f, 0.f};
    for (int ct = 0; ct < 8; ++ct) {
        if (ct < 7) LOAD_STAGE(ct + 1);          // prefetch to regs (T14)

        const short* wb = wlds;
        f32x4 acc[2][4];
        #pragma unroll
        for (int ctile = 0; ctile < 4; ++ctile) { acc[0][ctile] = z; acc[1][ctile] = z; }
        #pragma unroll
        for (int kc = 0; kc < 4; ++kc) {
            #pragma unroll
            for (int ctile = 0; ctile < 4; ++ctile) {
                int col = ctile * 16 + lr;
                bf16x8 b = *(const bf16x8*)&wb[col * 128 + (((kc * 4 + lh) ^ lr) * 8)];
                acc[0][ctile] = __builtin_amdgcn_mfma_f32_16x16x32_bf16(af[0][kc], b, acc[0][ctile], 0, 0, 0);
                acc[1][ctile] = __builtin_amdgcn_mfma_f32_16x16x32_bf16(af[1][kc], b, acc[1][ctile], 0, 0, 0);
            }
        }

        const int mat = ct >> 1, half = ct & 1;
        if (mat == 2) {
            #pragma unroll
            for (int qt = 0; qt < 2; ++qt)
                #pragma unroll
                for (int ctile = 0; ctile < 4; ++ctile) {
                    int chan = half * 64 + ctile * 16 + lr;
                    unsigned p0, p1;
                    asm("v_cvt_pk_bf16_f32 %0, %1, %2" : "=v"(p0)
                        : "v"(acc[qt][ctile][0]), "v"(acc[qt][ctile][1]));
                    asm("v_cvt_pk_bf16_f32 %0, %1, %2" : "=v"(p1)
                        : "v"(acc[qt][ctile][2]), "v"(acc[qt][ctile][3]));
                    uint2 st = { p0, p1 };
                    *(uint2*)(v_t + ((size_t)i * 128 + chan) * 256 + jb + wbase
                              + qt * 16 + lh * 4) = st;
                }
        } else {
            short* tw = &trans[w][0];
            #pragma unroll
            for (int qt = 0; qt < 2; ++qt)
                #pragma unroll
                for (int ctile = 0; ctile < 4; ++ctile) {
                    int col = ctile * 16 + lr;
                    if (mat == 3) {
                        float bgv = bg_s[half * 64 + col];
                        #pragma unroll
                        for (int r = 0; r < 4; ++r) {
                            float v = acc[qt][ctile][r] + bgv;
                            v = __builtin_amdgcn_rcpf(1.f + __builtin_amdgcn_exp2f(-v * LOG2E));
                            tw[(qt * 16 + lh * 4 + r) * 72 + col] = f2bf(v);
                        }
                    } else {
                        #pragma unroll
                        for (int r = 0; r < 4; ++r)
                            tw[(qt * 16 + lh * 4 + r) * 72 + col] = f2bf(acc[qt][ctile][r]);
                    }
                }
            short* G = (mat == 0) ? q_buf : (mat == 1) ? k_buf : g_buf;
            short* dst = G + (size_t)(P0 + (l >> 1)) * 128 + half * 64 + (l & 1) * 32;
            const short* src = tw + (l >> 1) * 72 + (l & 1) * 32;
            #pragma unroll
            for (int j = 0; j < 4; ++j)
                *(u32x4*)(dst + j * 8) = *(const u32x4*)(src + j * 8);
        }

        __syncthreads();                          // all waves done reading wlds
        if (ct < 7) {
            WRITE_STAGE();                        // overwrite with next chunk
            __syncthreads();                      // writes visible
        }
    }

    // w2d chunk -> nb4[h][(q>>2)*1024 + k*4 + (q&3)], q=i, k=j (R13 verified)
    {
        const short* w2 = wT + 5 * 16384 + lr * 128 + lh * 8;
        f32x4 acc0 = z, acc1 = z;
        #pragma unroll
        for (int kc = 0; kc < 4; ++kc) {
            bf16x8 b = *(const bf16x8*)(w2 + kc * 32);
            acc0 = __builtin_amdgcn_mfma_f32_16x16x32_bf16(af[0][kc], b, acc0, 0, 0, 0);
            acc1 = __builtin_amdgcn_mfma_f32_16x16x32_bf16(af[1][kc], b, acc1, 0, 0, 0);
        }
        if (lr < 4) {
            const int kc0 = (P0 & 255) + lh * 4;
            float* nbh = nb4 + (size_t)lr * 65536
                       + (size_t)(i >> 2) * 1024 + (i & 3);
            #pragma unroll
            for (int r = 0; r < 4; ++r) {
                nbh[(kc0 + r) * 4]      = acc0[r];
                nbh[(kc0 + 16 + r) * 4] = acc1[r];
            }
        }
    }
}

// ---------------------------------------------------------------------------
// Kernel 2: attention. 1024 blocks (i,h), 256 thr, wave = 64 queries;
// nb read as coalesced f32x4 from nb4, added post-MFMA in VALU.
// ---------------------------------------------------------------------------
__global__ __launch_bounds__(256) void attn_kernel(
    const float* __restrict__ mask,
    const short* __restrict__ q_buf, const short* __restrict__ k_buf,
    const short* __restrict__ v_t, const short* __restrict__ g_buf,
    const float* __restrict__ nb4, short* __restrict__ og_buf)
{
    __shared__ unsigned p_lds[4][64 * 20];
    __shared__ float bias_s[256];

    const int tid = threadIdx.x, bid = blockIdx.x;
    const int i = bid >> 2, h = bid & 3;

    bias_s[tid] = 1e9f * (mask[i * 256 + tid] - 1.f) * LOG2E;
    __syncthreads();

    const int w = tid >> 6, l = tid & 63, lr = l & 15, lh = l >> 4;
    const int qbase = w * 64;

    const short* qrow = q_buf + ((size_t)(i * 256 + qbase)) * 128 + h * 32;
    bf16x8 qf[4];
    #pragma unroll
    for (int qt = 0; qt < 4; ++qt)
        qf[qt] = *(const bf16x8*)(qrow + (qt * 16 + lr) * 128 + lh * 8);

    const short* krow = k_buf + ((size_t)(i * 256)) * 128 + h * 32 + lh * 8;
    const short* vrow = v_t + ((size_t)i * 128 + h * 32) * 256;
    const float* nbbase = nb4 + (size_t)h * 65536 + (size_t)(qbase >> 2) * 1024;
    unsigned* pw = &p_lds[w][0];

    f32x4 z = {0.f, 0.f, 0.f, 0.f};
    f32x4 o[4][2];
    float lsum[4][4];
    #pragma unroll
    for (int qt = 0; qt < 4; ++qt) {
        o[qt][0] = z; o[qt][1] = z;
        #pragma unroll
        for (int r = 0; r < 4; ++r) lsum[qt][r] = 0.f;
    }

    for (int kk = 0; kk < 256; kk += 32) {
        bf16x8 bk0 = *(const bf16x8*)(krow + (size_t)(kk + lr) * 128);
        bf16x8 bk1 = *(const bf16x8*)(krow + (size_t)(kk + 16 + lr) * 128);
        float b0 = bias_s[kk + lr], b1 = bias_s[kk + 16 + lr];
        #pragma unroll
        for (int qt = 0; qt < 4; ++qt) {
            const float* nbr = nbbase + (size_t)(qt * 4 + lh) * 1024 + (kk + lr) * 4;
            f32x4 cnb0 = *(const f32x4*)(nbr);
            f32x4 cnb1 = *(const f32x4*)(nbr + 64);   // k + 16
            f32x4 s0 = __builtin_amdgcn_mfma_f32_16x16x32_bf16(qf[qt], bk0, z, 0, 0, 0);
            f32x4 s1 = __builtin_amdgcn_mfma_f32_16x16x32_bf16(qf[qt], bk1, z, 0, 0, 0);
            #pragma unroll
            for (int r = 0; r < 4; ++r) {
                float p0 = __builtin_amdgcn_exp2f(s0[r] + b0 + cnb0[r]);
                float p1 = __builtin_amdgcn_exp2f(s1[r] + b1 + cnb1[r]);
                lsum[qt][r] += p0 + p1;
                unsigned pk;
                asm("v_cvt_pk_bf16_f32 %0, %1, %2" : "=v"(pk) : "v"(p0), "v"(p1));
                pw[(qt * 16 + lh * 4 + r) * 20 + lr] = pk;
            }
        }
        const short* vb = vrow + kk + lh * 4;
        uint2 a0 = *(const uint2*)(vb + (size_t)lr * 256);
        uint2 c0 = *(const uint2*)(vb + (size_t)lr * 256 + 16);
        uint2 a1 = *(const uint2*)(vb + (size_t)(16 + lr) * 256);
        uint2 c1 = *(const uint2*)(vb + (size_t)(16 + lr) * 256 + 16);
        u32x4 u0 = { __builtin_amdgcn_perm(c0.x, a0.x, 0x05040100),
                     __builtin_amdgcn_perm(c0.x, a0.x, 0x07060302),
                     __builtin_amdgcn_perm(c0.y, a0.y, 0x05040100),
                     __builtin_amdgcn_perm(c0.y, a0.y, 0x07060302) };
        u32x4 u1 = { __builtin_amdgcn_perm(c1.x, a1.x, 0x05040100),
                     __builtin_amdgcn_perm(c1.x, a1.x, 0x07060302),
                     __builtin_amdgcn_perm(c1.y, a1.y, 0x05040100),
                     __builtin_amdgcn_perm(c1.y, a1.y, 0x07060302) };
        bf16x8 bv0 = __builtin_bit_cast(bf16x8, u0);
        bf16x8 bv1 = __builtin_bit_cast(bf16x8, u1);
        #pragma unroll
        for (int qt = 0; qt < 4; ++qt) {
            bf16x8 pa = *(const bf16x8*)(pw + (qt * 16 + lr) * 20 + lh * 4);
            o[qt][0] = __builtin_amdgcn_mfma_f32_16x16x32_bf16(pa, bv0, o[qt][0], 0, 0, 0);
            o[qt][1] = __builtin_amdgcn_mfma_f32_16x16x32_bf16(pa, bv1, o[qt][1], 0, 0, 0);
        }
    }

    float inv[4][4];
    #pragma unroll
    for (int qt = 0; qt < 4; ++qt)
        #pragma unroll
        for (int r = 0; r < 4; ++r) {
            float v = lsum[qt][r];
            v += __shfl_xor(v, 1); v += __shfl_xor(v, 2);
            v += __shfl_xor(v, 4); v += __shfl_xor(v, 8);
            inv[qt][r] = __builtin_amdgcn_rcpf(v);
        }

    short* ow = (short*)pw;
    const short* grow = g_buf + ((size_t)(i * 256 + qbase)) * 128 + h * 32;
    #pragma unroll
    for (int qt = 0; qt < 4; ++qt)
        #pragma unroll
        for (int ct = 0; ct < 2; ++ct) {
            int c = ct * 16 + lr;
            #pragma unroll
            for (int r = 0; r < 4; ++r) {
                int q = qt * 16 + lh * 4 + r;
                float gf = bf2f((unsigned short)grow[(size_t)q * 128 + c]);
                ow[q * 40 + c] = f2bf(o[qt][ct][r] * inv[qt][r] * gf);
            }
        }
    short* og_row = og_buf + ((size_t)(i * 256 + qbase)) * 128 + h * 32;
    #pragma unroll
    for (int j = 0; j < 4; ++j) {
        u32x4 t = *(const u32x4*)(ow + l * 40 + j * 8);
        *(u32x4*)(og_row + (size_t)l * 128 + j * 8) = t;
    }
}

// ---------------------------------------------------------------------------
// Kernel 3: output projection. 1024 blocks (64 pos), 256 thr.
// ---------------------------------------------------------------------------
__global__ __launch_bounds__(256) void out_kernel(
    const short* __restrict__ og_buf, const short* __restrict__ wT,
    const float* __restrict__ bo, float* __restrict__ out)
{
    const int tid = threadIdx.x;
    const int pbase = blockIdx.x * 64;
    const int w = tid >> 6, l = tid & 63, lr = l & 15, lh = l >> 4;

    bf16x8 af[4][4];
    #pragma unroll
    for (int qt = 0; qt < 4; ++qt) {
        const short* rp = og_buf + (size_t)(pbase + qt * 16 + lr) * 128 + lh * 8;
        #pragma unroll
        for (int kc = 0; kc < 4; ++kc) af[qt][kc] = *(const bf16x8*)(rp + kc * 32);
    }
    const short* wo_t = wT + 4 * 16384;
    f32x4 z = {0.f, 0.f, 0.f, 0.f};
    #pragma unroll
    for (int ct = 0; ct < 2; ++ct) {
        int col = w * 32 + ct * 16 + lr;
        f32x4 acc0 = z, acc1 = z, acc2 = z, acc3 = z;
        #pragma unroll
        for (int kc = 0; kc < 4; ++kc) {
            bf16x8 b = *(const bf16x8*)(wo_t + col * 128 + kc * 32 + lh * 8);
            acc0 = __builtin_amdgcn_mfma_f32_16x16x32_bf16(af[0][kc], b, acc0, 0, 0, 0);
            acc1 = __builtin_amdgcn_mfma_f32_16x16x32_bf16(af[1][kc], b, acc1, 0, 0, 0);
            acc2 = __builtin_amdgcn_mfma_f32_16x16x32_bf16(af[2][kc], b, acc2, 0, 0, 0);
            acc3 = __builtin_amdgcn_mfma_f32_16x16x32_bf16(af[3][kc], b, acc3, 0, 0, 0);
        }
        f32x4 acc[4] = {acc0, acc1, acc2, acc3};
        float bov = bo[col];
        #pragma unroll
        for (int qt = 0; qt < 4; ++qt)
            #pragma unroll
            for (int r = 0; r < 4; ++r)
                out[(size_t)(pbase + qt * 16 + lh * 4 + r) * 128 + col] =
                    acc[qt][r] + bov;
    }
}

// ---------------------------------------------------------------------------
extern "C" void kernel_launch(void* const* d_in, const int* in_sizes, int n_in,
                              void* d_out, int out_size, void* d_ws, size_t ws_size,
                              hipStream_t stream) {
    const float* act  = (const float*)d_in[0];
    const float* mask = (const float*)d_in[1];
    const float* ln_w = (const float*)d_in[2];
    const float* ln_b = (const float*)d_in[3];
    const float* w2d  = (const float*)d_in[4];
    const float* wq   = (const float*)d_in[5];
    const float* wk   = (const float*)d_in[6];
    const float* wv   = (const float*)d_in[7];
    const float* wg   = (const float*)d_in[8];
    const float* bg   = (const float*)d_in[9];
    const float* wo   = (const float*)d_in[10];
    const float* bo   = (const float*)d_in[11];
    float* out = (float*)d_out;

    char* ws = (char*)d_ws;
    short* q_buf  = (short*)(ws);
    short* k_buf  = (short*)(ws + 16777216);
    short* v_t    = (short*)(ws + 2 * 16777216);
    short* og_buf = (short*)(ws + 3 * 16777216);
    short* g_buf  = (short*)(ws + 4 * 16777216);
    float* nb4    = (float*)(ws + 5 * 16777216);
    short* wT     = (short*)(ws + 5 * 16777216 + 1048576);

    prep_kernel<<<328, 256, 0, stream>>>(wq, wk, wv, wg, wo, w2d, wT);
    proj_kernel<<<512, 256, 0, stream>>>(act, ln_w, ln_b, bg, wT,
                                         q_buf, k_buf, v_t, g_buf, nb4);
    attn_kernel<<<1024, 256, 0, stream>>>(mask, q_buf, k_buf, v_t, g_buf,
                                          nb4, og_buf);
    out_kernel<<<1024, 256, 0, stream>>>(og_buf, wT, bo, out);
}